// Round 7
// baseline (449.514 us; speedup 1.0000x reference)
//
#include <hip/hip_runtime.h>
#include <math.h>

#define NN_K 32
#define E_DIM 512
#define CLAMP_V 10000.0f
#define NBLK 512

typedef __attribute__((ext_vector_type(8))) short short8;
typedef __attribute__((ext_vector_type(4))) float f32x4;

// bf16 RTNE, bit-level
__device__ __forceinline__ unsigned short f2bf(float x) {
  unsigned u = __float_as_uint(x);
  unsigned r = u + 0x7fffu + ((u >> 16) & 1u);
  return (unsigned short)(r >> 16);
}
__device__ __forceinline__ float bf2f_bits(short h) {
  return __uint_as_float(((unsigned)(unsigned short)h) << 16);
}

__device__ __forceinline__ void async16(const void* g, void* l) {
  __builtin_amdgcn_global_load_lds((const __attribute__((address_space(1))) void*)g,
                                   (__attribute__((address_space(3))) void*)l, 16, 0, 0);
}

// ---------------------------------------------------------------------------
// Grid barrier: device-scope atomics, one fresh counter per barrier point.
// All NBLK blocks are co-resident by construction (launch_bounds(256,2) =>
// >=2 blocks/CU resources; 512 = 2 x 256 CUs). Bounded spin: a failure
// degrades to wrong-answer (test-caught), never a hang.
// ---------------------------------------------------------------------------
__device__ __forceinline__ void grid_bar(unsigned* bar, int idx, int nb) {
  __syncthreads();
  __threadfence();                 // release: push our writes to coherence pt
  if (threadIdx.x == 0) {
    atomicAdd(&bar[idx], 1u);
    unsigned spin = 0;
    while (atomicAdd(&bar[idx], 0u) < (unsigned)nb) {
      __builtin_amdgcn_s_sleep(2);
      if (++spin > (1u << 20)) break;
    }
  }
  __syncthreads();
  __threadfence();                 // acquire: invalidate caches before reads
}

__global__ __launch_bounds__(64) void init_bar(unsigned* bar) {
  if (threadIdx.x < 8) bar[threadIdx.x] = 0;
}

// ---------------------------------------------------------------------------
// bf16 MFMA GEMM core, 64x128 tile, double-buffered vmcnt(3)+s_barrier pipe.
// (R2 known-good; 64x128 beats 128x128 at this problem size, R4.)
// ---------------------------------------------------------------------------
__device__ __forceinline__ void gemm_core(
    char* smem,
    const short* __restrict__ A, const short* __restrict__ W,
    const float* __restrict__ bias,
    float* __restrict__ outf, short* __restrict__ outb,
    int out_ld, int out_c0,
    int M, int row0, int col0, bool doClamp)
{
  short* sA = (short*)smem;             // [2][64*32]
  short* sB = (short*)(smem + 8192);    // [2][128*32]
  int tid = threadIdx.x;
  int cr = tid >> 2;
  int ck = (tid & 3) << 3;
  const short* gA = A + (size_t)(row0 + cr) * 512 + ck;
  const short* gB = W + (size_t)(col0 + cr) * 512 + ck;
  int lo = tid * 8, loB1 = (tid + 256) * 8;
  const size_t rstep = (size_t)64 * 512;

  int lane = tid & 63, wv_ = tid >> 6;
  int wn = wv_ << 5;
  int lr = lane & 15, lq = lane >> 4;

#define STAGE(t, b) do { \
    async16(gA + (t) * 32,         sA + (b) * 2048 + lo); \
    async16(gB + (t) * 32,         sB + (b) * 4096 + lo); \
    async16(gB + (t) * 32 + rstep, sB + (b) * 4096 + loB1); } while (0)

  STAGE(0, 0);
  STAGE(1, 1);

  f32x4 acc[4][2];
  #pragma unroll
  for (int i = 0; i < 4; ++i)
    #pragma unroll
    for (int j = 0; j < 2; ++j)
      acc[i][j] = (f32x4){0.f, 0.f, 0.f, 0.f};

  #pragma unroll
  for (int it = 0; it < 16; ++it) {
    int cur = it & 1;
    if (it == 15) asm volatile("s_waitcnt vmcnt(0)\ns_barrier" ::: "memory");
    else          asm volatile("s_waitcnt vmcnt(3)\ns_barrier" ::: "memory");

    short8 af[4], bf[2];
    #pragma unroll
    for (int i = 0; i < 4; ++i)
      af[i] = *(const short8*)&sA[cur * 2048 + ((i << 4) + lr) * 32 + (lq << 3)];
    #pragma unroll
    for (int j = 0; j < 2; ++j)
      bf[j] = *(const short8*)&sB[cur * 4096 + (wn + (j << 4) + lr) * 32 + (lq << 3)];
    #pragma unroll
    for (int i = 0; i < 4; ++i)
      #pragma unroll
      for (int j = 0; j < 2; ++j)
        acc[i][j] = __builtin_amdgcn_mfma_f32_16x16x32_bf16(af[i], bf[j], acc[i][j], 0, 0, 0);

    asm volatile("s_waitcnt lgkmcnt(0)\ns_barrier" ::: "memory");
    if (it + 2 < 16) STAGE(it + 2, cur);
  }
#undef STAGE

  #pragma unroll
  for (int j = 0; j < 2; ++j) {
    int gcol = col0 + wn + (j << 4) + lr;
    float bv_ = bias[gcol];
    #pragma unroll
    for (int i = 0; i < 4; ++i) {
      #pragma unroll
      for (int r = 0; r < 4; ++r) {
        int grow = row0 + (i << 4) + (lq << 2) + r;
        if (grow < M) {
          float v = acc[i][j][r] + bv_;
          if (doClamp) {
            v = isnan(v) ? 0.0f : v;
            v = fminf(fmaxf(v, -CLAMP_V), CLAMP_V);
          }
          if (outf) outf[(size_t)grow * 512 + gcol] = v;
          else      outb[(size_t)grow * out_ld + out_c0 + gcol] = (short)f2bf(v);
        }
      }
    }
  }
}

// ---------------------------------------------------------------------------
// topk unit: single-pass 2048-bin histogram select (R2 known-good).
// ---------------------------------------------------------------------------
__device__ __forceinline__ void topk_unit(
    int n, const float* __restrict__ cent, int* __restrict__ topk, int N,
    char* smem, unsigned* waveSums, unsigned& selB, unsigned& selNeed,
    unsigned& cnt, unsigned& tcnt)
{
  unsigned* wh   = (unsigned*)smem;            // [4][1024] packed, 16 KB
  unsigned* tieB = (unsigned*)(smem + 16384);  // 1024 bits, 4 KB
  unsigned* tieI = (unsigned*)(smem + 20480);  // 1024 idx,  4 KB

  int t = threadIdx.x;
  int lane = t & 63, wid = t >> 6;
  const float4* cq = (const float4*)cent;
  float4 c = cq[n];
  float cx = c.x, cy = c.y, cz = c.z;

  #pragma unroll
  for (int i = 0; i < 16; ++i) wh[t + i * 256] = 0;

  unsigned bits[8];
  #pragma unroll
  for (int r = 0; r < 8; ++r) {
    int m = t + (r << 8);
    unsigned b = 0xFFFFFFFFu;
    if (m < N) {
      float4 cm = cq[m];
      float dx = cx - cm.x, dy = cy - cm.y, dz = cz - cm.z;
      float dist = sqrtf(dx*dx + dy*dy + dz*dz);
      b = __float_as_uint(dist);
    }
    bits[r] = b;
  }
  __syncthreads();

  unsigned* myh = wh + (wid << 10);
  #pragma unroll
  for (int r = 0; r < 8; ++r) {
    if (bits[r] != 0xFFFFFFFFu) {
      unsigned bin = bits[r] >> 20;
      atomicAdd(&myh[bin >> 1], 1u << ((bin & 1) << 4));
    }
  }
  __syncthreads();

  unsigned bc[8];
  unsigned tot = 0;
  #pragma unroll
  for (int w = 0; w < 4; ++w) {
    int iw = (t << 2) + w;
    unsigned s = wh[iw] + wh[1024 + iw] + wh[2048 + iw] + wh[3072 + iw];
    bc[w * 2]     = s & 0xFFFFu;
    bc[w * 2 + 1] = s >> 16;
    tot += (s & 0xFFFFu) + (s >> 16);
  }
  unsigned scan = tot;
  #pragma unroll
  for (int o = 1; o < 64; o <<= 1) {
    unsigned u = __shfl_up(scan, o);
    if (lane >= o) scan += u;
  }
  if (lane == 63) waveSums[wid] = scan;
  __syncthreads();
  unsigned off = 0;
  for (int w = 0; w < wid; ++w) off += waveSums[w];
  unsigned incl = scan + off;
  unsigned excl = incl - tot;
  if (excl < NN_K && incl >= NN_K) {
    unsigned cacc = excl;
    #pragma unroll
    for (int b = 0; b < 8; ++b) {
      if (cacc + bc[b] >= NN_K) { selB = (unsigned)(t * 8 + b); selNeed = NN_K - cacc; break; }
      cacc += bc[b];
    }
  }
  if (t == 0) { cnt = 0; tcnt = 0; }
  __syncthreads();

  unsigned B = selB;
  #pragma unroll
  for (int r = 0; r < 8; ++r) {
    if (bits[r] != 0xFFFFFFFFu) {
      unsigned bin = bits[r] >> 20;
      if (bin < B) {
        unsigned slot = atomicAdd(&cnt, 1u);
        topk[n * NN_K + slot] = t + (r << 8);
      } else if (bin == B) {
        unsigned tp = atomicAdd(&tcnt, 1u);
        if (tp < 1024u) { tieB[tp] = bits[r]; tieI[tp] = (unsigned)(t + (r << 8)); }
      }
    }
  }
  __syncthreads();

  if (t < 64) {
    unsigned base = cnt;
    unsigned need = selNeed;
    unsigned tn = tcnt > 1024u ? 1024u : tcnt;
    for (unsigned j = lane; j < tn; j += 64) {
      unsigned kb = tieB[j], ki = tieI[j];
      unsigned rank = 0;
      for (unsigned i = 0; i < tn; ++i) {
        unsigned ib = tieB[i];
        rank += (ib < kb) || (ib == kb && tieI[i] < ki);
      }
      if (rank < need) topk[n * NN_K + base + rank] = (int)ki;
    }
  }
}

// ---------------------------------------------------------------------------
// attn row, 256-thread variant: 4 head-groups of 64 lanes, 2-head loop.
// Destaged K reads (R5 known-good math, same accumulation order).
// ---------------------------------------------------------------------------
__device__ __forceinline__ void attn_row(
    int n, const float* __restrict__ qb, const short* __restrict__ kv,
    const int* __restrict__ topk, short* __restrict__ ctx_bf, char* smem, int N)
{
  int* sidx = (int*)smem;
  float* plds = (float*)(smem + 128);
  int tid = threadIdx.x;
  size_t rb = (size_t)n * E_DIM;

  if (n >= N) {
    #pragma unroll
    for (int j = tid; j < E_DIM; j += 256) ctx_bf[rb + j] = 0;
    return;
  }

  if (tid < NN_K) sidx[tid] = topk[n * NN_K + tid];
  __syncthreads();

  int h4 = tid >> 6, lane = tid & 63;
  int jk = lane & 31, half = lane >> 5;

  #pragma unroll
  for (int hi = 0; hi < 2; ++hi) {
    int hh = h4 + hi * 4;
    int dbase = hh * 64 + half * 32;

    float qv[32];
    {
      const float4* qs = (const float4*)(qb + rb + dbase);
      #pragma unroll
      for (int b = 0; b < 8; ++b) {
        float4 f = qs[b];
        qv[b*4+0] = f.x; qv[b*4+1] = f.y; qv[b*4+2] = f.z; qv[b*4+3] = f.w;
      }
    }

    float s = 0.f;
    {
      const short8* krow = (const short8*)(kv + (size_t)sidx[jk] * 1024 + dbase);
      #pragma unroll
      for (int b = 0; b < 4; ++b) {
        short8 kk = krow[b];
        #pragma unroll
        for (int e = 0; e < 8; ++e)
          s += qv[b * 8 + e] * bf2f_bits(kk[e]);
      }
    }
    s += __shfl_xor(s, 32);
    s *= 0.125f;

    float mx = s;
    #pragma unroll
    for (int o = 16; o > 0; o >>= 1) mx = fmaxf(mx, __shfl_xor(mx, o));
    float p = expf(s - mx);
    float l = p;
    #pragma unroll
    for (int o = 16; o > 0; o >>= 1) l += __shfl_xor(l, o);
    p *= (1.0f / l);
    if (half == 0) plds[hh * 32 + jk] = p;
    __syncthreads();

    float pv[32];
    #pragma unroll
    for (int b = 0; b < 8; ++b) {
      float4 f = *(const float4*)&plds[hh * 32 + b * 4];
      pv[b*4+0] = f.x; pv[b*4+1] = f.y; pv[b*4+2] = f.z; pv[b*4+3] = f.w;
    }

    int off = 512 + hh * 64 + lane;
    float acc = 0.f;
    #pragma unroll
    for (int j = 0; j < NN_K; ++j)
      acc += pv[j] * bf2f_bits(kv[(size_t)sidx[j] * 1024 + off]);
    ctx_bf[rb + hh * 64 + lane] = (short)f2bf(acc);
  }
}

// ---------------------------------------------------------------------------
// Fused kernel: 4 phases over a custom grid barrier. Normal launch.
// 512 blocks x 256 thr; __launch_bounds__(256,2) + 24.7KB LDS guarantee
// 2 blocks/CU co-residency for the barrier.
// ---------------------------------------------------------------------------
__global__ __launch_bounds__(256, 2) void mega_kernel(
    const float* __restrict__ x, const float* __restrict__ coords9,
    const float* __restrict__ prompt,
    const float* __restrict__ w1, const float* __restrict__ b1,
    const float* __restrict__ ln_g, const float* __restrict__ ln_b,
    const float* __restrict__ wq, const float* __restrict__ wk,
    const float* __restrict__ wv,
    const float* __restrict__ bq, const float* __restrict__ bk,
    const float* __restrict__ bv,
    const float* __restrict__ wo, const float* __restrict__ bo,
    short* __restrict__ w_bf, short* __restrict__ pos_bf,
    float* __restrict__ cent, int* __restrict__ topk,
    float* __restrict__ qb, short* __restrict__ kv,
    short* __restrict__ ctx_bf, float* __restrict__ outp,
    unsigned* __restrict__ bar, int N, int Mpad)
{
  __shared__ __align__(16) char smem[24576];
  __shared__ float red[4];
  __shared__ unsigned waveSums[4];
  __shared__ unsigned selB, selNeed, cnt, tcnt;

  int t = threadIdx.x;
  int nb = gridDim.x;

  // ============ phase A: wconv + pos (+cent) ============
  for (int u = blockIdx.x; u < 256 + Mpad; u += nb) {
    if (u < 256) {
      #pragma unroll
      for (int i = 0; i < 4; ++i) {
        int v = u * 256 + t + i * 65536;
        int m = v >> 16;
        int e = v & 0xffff;
        const float* src = m == 0 ? wq : (m == 1 ? wk : (m == 2 ? wv : wo));
        float4 f = ((const float4*)src)[e];
        short4 h;
        h.x = (short)f2bf(f.x); h.y = (short)f2bf(f.y);
        h.z = (short)f2bf(f.z); h.w = (short)f2bf(f.w);
        ((short4*)w_bf)[v] = h;
      }
    } else {
      int n = u - 256;
      size_t rb = (size_t)n * E_DIM;
      if (n >= N) {
        #pragma unroll
        for (int j = t; j < E_DIM; j += 256) pos_bf[rb + j] = 0;
      } else {
        float g = 0.f;
        if (t < 128) {
          const float* c9 = coords9 + n * 9;
          float c0 = (c9[0] + c9[3] + c9[6]) / 3.0f;
          float c1 = (c9[1] + c9[4] + c9[7]) / 3.0f;
          float c2 = (c9[2] + c9[5] + c9[8]) / 3.0f;
          if (t == 0) {
            float4 c; c.x = c0; c.y = c1; c.z = c2; c.w = 0.f;
            ((float4*)cent)[n] = c;
          }
          float pre = c0 * w1[t*3+0] + c1 * w1[t*3+1] + c2 * w1[t*3+2] + b1[t];
          g = 0.5f * pre * (1.0f + erff(pre * 0.70710678118654752440f));
          float s = g;
          #pragma unroll
          for (int o = 32; o > 0; o >>= 1) s += __shfl_xor(s, o);
          if ((t & 63) == 0) red[t >> 6] = s;
        }
        __syncthreads();
        float mu = (red[0] + red[1]) * (1.0f / 128.0f);
        float d = g - mu;
        if (t < 128) {
          float s2 = d * d;
          #pragma unroll
          for (int o = 32; o > 0; o >>= 1) s2 += __shfl_xor(s2, o);
          if ((t & 63) == 0) red[2 + (t >> 6)] = s2;
        }
        __syncthreads();
        if (t < 128) {
          float var = (red[2] + red[3]) * (1.0f / 128.0f);
          float y = d * rsqrtf(var + 1e-5f) * ln_g[t] + ln_b[t];
          pos_bf[rb + 384 + t] = (short)f2bf(y);
        }
        #pragma unroll
        for (int j = t; j < 384; j += 256)
          pos_bf[rb + j] = (short)f2bf(x[rb + j] + prompt[j]);
      }
    }
    __syncthreads();
  }
  grid_bar(bar, 0, nb);

  // ============ phase B: QKV GEMMs + topk ============
  for (int u = blockIdx.x; u < 384 + N; u += nb) {
    if (u < 384) {
      int bx = u & 31, by = u >> 5;
      int sel = by >> 2, nblk = by & 3;
      int r0 = bx * 64, c0 = nblk * 128;
      if (sel == 0)
        gemm_core(smem, pos_bf, w_bf, bq, qb, nullptr, 512, 0, Mpad, r0, c0, false);
      else if (sel == 1)
        gemm_core(smem, pos_bf, w_bf + 262144, bk, nullptr, kv, 1024, 0, Mpad, r0, c0, false);
      else
        gemm_core(smem, pos_bf, w_bf + 2 * 262144, bv, nullptr, kv, 1024, 512, Mpad, r0, c0, false);
    } else {
      topk_unit(u - 384, cent, topk, N, smem, waveSums, selB, selNeed, cnt, tcnt);
    }
    __syncthreads();
  }
  grid_bar(bar, 1, nb);

  // ============ phase C: attn ============
  for (int n = blockIdx.x; n < Mpad; n += nb) {
    attn_row(n, qb, kv, topk, ctx_bf, smem, N);
    __syncthreads();
  }
  grid_bar(bar, 2, nb);

  // ============ phase D: out GEMM ============
  for (int u = blockIdx.x; u < 128; u += nb) {
    int bx = u & 31, by = u >> 5;
    gemm_core(smem, ctx_bf, w_bf + (size_t)3 * 262144, bo, outp, nullptr, 512, 0, N,
              bx * 64, by * 128, true);
  }
}

// ---------------------------------------------------------------------------
extern "C" void kernel_launch(void* const* d_in, const int* in_sizes, int n_in,
                              void* d_out, int out_size, void* d_ws, size_t ws_size,
                              hipStream_t stream) {
  const float* x       = (const float*)d_in[0];
  const float* coords9 = (const float*)d_in[1];
  const float* prompt  = (const float*)d_in[2];
  const float* pos_w1  = (const float*)d_in[3];
  const float* pos_b1  = (const float*)d_in[4];
  const float* ln_g    = (const float*)d_in[5];
  const float* ln_b    = (const float*)d_in[6];
  const float* wq      = (const float*)d_in[7];
  const float* wk      = (const float*)d_in[8];
  const float* wv      = (const float*)d_in[9];
  const float* bq      = (const float*)d_in[10];
  const float* bk      = (const float*)d_in[11];
  const float* bv      = (const float*)d_in[12];
  const float* wo      = (const float*)d_in[13];
  const float* bo      = (const float*)d_in[14];

  int N = in_sizes[1] / 9;                       // 2000
  int Mpad = (N + 127) & ~127;                   // 2048
  size_t PE = (size_t)Mpad * E_DIM;

  char* p = (char*)d_ws;
  short* pos_bf = (short*)p; p += PE * 2;                      // 2 MB
  short* w_bf   = (short*)p; p += (size_t)4 * 512 * 512 * 2;   // 2 MB
  float* qb     = (float*)p; p += PE * 4;                      // 4 MB
  short* kv_bf  = (short*)p; p += PE * 2 * 2;                  // 4 MB (k|v)
  short* ctx_bf = (short*)p; p += PE * 2;                      // 2 MB
  int*   topk   = (int*)p;   p += (size_t)Mpad * NN_K * 4;     // 256 KB
  float* cent   = (float*)p; p += (size_t)Mpad * 16;           // 32 KB
  unsigned* bar = (unsigned*)p;                                // 32 B

  float* outp = (float*)d_out;

  init_bar<<<1, 64, 0, stream>>>(bar);
  mega_kernel<<<NBLK, 256, 0, stream>>>(
      x, coords9, prompt, pos_w1, pos_b1, ln_g, ln_b,
      wq, wk, wv, bq, bk, bv, wo, bo,
      w_bf, pos_bf, cent, topk, qb, kv_bf, ctx_bf, outp,
      bar, N, Mpad);
}

// Round 8
// 138.213 us; speedup vs baseline: 3.2523x; 3.2523x over previous
//
#include <hip/hip_runtime.h>
#include <math.h>

#define NN_K 32
#define E_DIM 512
#define CLAMP_V 10000.0f

typedef __attribute__((ext_vector_type(8))) short short8;
typedef __attribute__((ext_vector_type(4))) float f32x4;

// bf16 RTNE, bit-level
__device__ __forceinline__ unsigned short f2bf(float x) {
  unsigned u = __float_as_uint(x);
  unsigned r = u + 0x7fffu + ((u >> 16) & 1u);
  return (unsigned short)(r >> 16);
}
__device__ __forceinline__ float bf2f_bits(short h) {
  return __uint_as_float(((unsigned)(unsigned short)h) << 16);
}

__device__ __forceinline__ void async16(const void* g, void* l) {
  __builtin_amdgcn_global_load_lds((const __attribute__((address_space(1))) void*)g,
                                   (__attribute__((address_space(3))) void*)l, 16, 0, 0);
}

// ---------------------------------------------------------------------------
// Kernel 1 (front): wconv + pos.
//   blocks [0,256):        wconv  — 4 weight matrices fp32 -> bf16
//   blocks [256,256+Mpad): pos    — centroid+Linear(3,128)+GELU+LN+concat
//                                   also writes packed centroid float4 (for topk)
// ---------------------------------------------------------------------------
__global__ __launch_bounds__(256) void front_kernel(
    const float* __restrict__ x, const float* __restrict__ coords9,
    const float* __restrict__ prompt,
    const float* __restrict__ w1, const float* __restrict__ b1,
    const float* __restrict__ ln_g, const float* __restrict__ ln_b,
    const float* __restrict__ wq, const float* __restrict__ wk,
    const float* __restrict__ wv, const float* __restrict__ wo,
    short* __restrict__ w_bf, short* __restrict__ pos_bf,
    float* __restrict__ cent, int N)
{
  int blk = blockIdx.x;
  int t = threadIdx.x;

  if (blk < 256) {
    #pragma unroll
    for (int i = 0; i < 4; ++i) {
      int v = blk * 256 + t + i * 65536;
      int m = v >> 16;
      int e = v & 0xffff;
      const float* src = m == 0 ? wq : (m == 1 ? wk : (m == 2 ? wv : wo));
      float4 f = ((const float4*)src)[e];
      short4 h;
      h.x = (short)f2bf(f.x); h.y = (short)f2bf(f.y);
      h.z = (short)f2bf(f.z); h.w = (short)f2bf(f.w);
      ((short4*)w_bf)[v] = h;
    }
    return;
  }

  // ---- pos: one row per block; threads t<128 run the encoder ----
  int n = blk - 256;
  size_t rb = (size_t)n * E_DIM;
  if (n >= N) {
    #pragma unroll
    for (int j = t; j < E_DIM; j += 256) pos_bf[rb + j] = 0;
    return;
  }
  __shared__ float red[4];
  float g = 0.f;
  if (t < 128) {
    const float* c9 = coords9 + n * 9;
    float c0 = (c9[0] + c9[3] + c9[6]) / 3.0f;
    float c1 = (c9[1] + c9[4] + c9[7]) / 3.0f;
    float c2 = (c9[2] + c9[5] + c9[8]) / 3.0f;
    if (t == 0) {
      float4 c; c.x = c0; c.y = c1; c.z = c2; c.w = 0.f;
      ((float4*)cent)[n] = c;     // bit-identical to topk's dist inputs
    }
    float pre = c0 * w1[t*3+0] + c1 * w1[t*3+1] + c2 * w1[t*3+2] + b1[t];
    g = 0.5f * pre * (1.0f + erff(pre * 0.70710678118654752440f));
    float s = g;
    #pragma unroll
    for (int o = 32; o > 0; o >>= 1) s += __shfl_xor(s, o);
    if ((t & 63) == 0) red[t >> 6] = s;
  }
  __syncthreads();
  float mu = (red[0] + red[1]) * (1.0f / 128.0f);
  float d = g - mu;
  if (t < 128) {
    float s2 = d * d;
    #pragma unroll
    for (int o = 32; o > 0; o >>= 1) s2 += __shfl_xor(s2, o);
    if ((t & 63) == 0) red[2 + (t >> 6)] = s2;
  }
  __syncthreads();
  if (t < 128) {
    float var = (red[2] + red[3]) * (1.0f / 128.0f);
    float y = d * rsqrtf(var + 1e-5f) * ln_g[t] + ln_b[t];
    pos_bf[rb + 384 + t] = (short)f2bf(y);
  }
  // x+prompt pass, vectorized (G13): 96 float4 loads, short4 stores
  if (t < 96) {
    float4 xv = ((const float4*)(x + rb))[t];
    float4 pv = ((const float4*)prompt)[t];
    short4 h;
    h.x = (short)f2bf(xv.x + pv.x);
    h.y = (short)f2bf(xv.y + pv.y);
    h.z = (short)f2bf(xv.z + pv.z);
    h.w = (short)f2bf(xv.w + pv.w);
    ((short4*)(pos_bf + rb))[t] = h;
  }
}

// ---------------------------------------------------------------------------
// bf16 MFMA GEMM core, 64x128 tile, double-buffered vmcnt(3)+s_barrier pipe.
// 256 thr = 4 waves; wave w computes 64 rows x 32 cols (acc 4x2).
// 24 KB LDS (caller-provided: sA at 0, sB at 8192 bytes).
// 64x128 over 128x128: at 2048x512x512 grid width beats per-block density (R4).
// ---------------------------------------------------------------------------
__device__ __forceinline__ void gemm_core(
    char* smem,
    const short* __restrict__ A, const short* __restrict__ W,
    const float* __restrict__ bias,
    float* __restrict__ outf, short* __restrict__ outb,
    int out_ld, int out_c0,
    int M, int row0, int col0, bool doClamp)
{
  short* sA = (short*)smem;             // [2][64*32]
  short* sB = (short*)(smem + 8192);    // [2][128*32]
  int tid = threadIdx.x;
  int cr = tid >> 2;
  int ck = (tid & 3) << 3;
  const short* gA = A + (size_t)(row0 + cr) * 512 + ck;
  const short* gB = W + (size_t)(col0 + cr) * 512 + ck;
  int lo = tid * 8, loB1 = (tid + 256) * 8;
  const size_t rstep = (size_t)64 * 512;

  int lane = tid & 63, wv_ = tid >> 6;
  int wn = wv_ << 5;                       // wave col offset 0/32/64/96
  int lr = lane & 15, lq = lane >> 4;

#define STAGE(t, b) do { \
    async16(gA + (t) * 32,         sA + (b) * 2048 + lo); \
    async16(gB + (t) * 32,         sB + (b) * 4096 + lo); \
    async16(gB + (t) * 32 + rstep, sB + (b) * 4096 + loB1); } while (0)

  STAGE(0, 0);
  STAGE(1, 1);

  f32x4 acc[4][2];
  #pragma unroll
  for (int i = 0; i < 4; ++i)
    #pragma unroll
    for (int j = 0; j < 2; ++j)
      acc[i][j] = (f32x4){0.f, 0.f, 0.f, 0.f};

  #pragma unroll
  for (int it = 0; it < 16; ++it) {
    int cur = it & 1;
    if (it == 15) asm volatile("s_waitcnt vmcnt(0)\ns_barrier" ::: "memory");
    else          asm volatile("s_waitcnt vmcnt(3)\ns_barrier" ::: "memory");

    short8 af[4], bf[2];
    #pragma unroll
    for (int i = 0; i < 4; ++i)
      af[i] = *(const short8*)&sA[cur * 2048 + ((i << 4) + lr) * 32 + (lq << 3)];
    #pragma unroll
    for (int j = 0; j < 2; ++j)
      bf[j] = *(const short8*)&sB[cur * 4096 + (wn + (j << 4) + lr) * 32 + (lq << 3)];
    #pragma unroll
    for (int i = 0; i < 4; ++i)
      #pragma unroll
      for (int j = 0; j < 2; ++j)
        acc[i][j] = __builtin_amdgcn_mfma_f32_16x16x32_bf16(af[i], bf[j], acc[i][j], 0, 0, 0);

    asm volatile("s_waitcnt lgkmcnt(0)\ns_barrier" ::: "memory");
    if (it + 2 < 16) STAGE(it + 2, cur);
  }
#undef STAGE

  #pragma unroll
  for (int j = 0; j < 2; ++j) {
    int gcol = col0 + wn + (j << 4) + lr;
    float bv_ = bias[gcol];
    #pragma unroll
    for (int i = 0; i < 4; ++i) {
      #pragma unroll
      for (int r = 0; r < 4; ++r) {
        int grow = row0 + (i << 4) + (lq << 2) + r;
        if (grow < M) {
          float v = acc[i][j][r] + bv_;
          if (doClamp) {
            v = isnan(v) ? 0.0f : v;
            v = fminf(fmaxf(v, -CLAMP_V), CLAMP_V);
          }
          if (outf) outf[(size_t)grow * 512 + gcol] = v;
          else      outb[(size_t)grow * out_ld + out_c0 + gcol] = (short)f2bf(v);
        }
      }
    }
  }
}

// ---------------------------------------------------------------------------
// Kernel 2 (merged): QKV GEMMs (blockIdx.y < 12) + topk single-pass
// histogram select (blockIdx.y >= 12). gridDim.x = Mpad/64 = 32.
// ---------------------------------------------------------------------------
__global__ __launch_bounds__(256) void qkv_topk(
    const short* __restrict__ A, const short* __restrict__ Wb,
    const float* __restrict__ bq, const float* __restrict__ bk, const float* __restrict__ bv,
    float* __restrict__ qb, short* __restrict__ kv,
    const float* __restrict__ cent, int* __restrict__ topk,
    int M, int N)
{
  __shared__ __align__(16) char smem[24576];   // gemm sA/sB  OR  topk hists+ties
  __shared__ unsigned waveSums[4];
  __shared__ unsigned selB, selNeed;
  __shared__ unsigned cnt, tcnt;

  int by = blockIdx.y;
  if (by < 12) {
    int sel = by >> 2;
    int nblk = by & 3;
    int r0 = blockIdx.x * 64, c0 = nblk * 128;
    if (sel == 0)
      gemm_core(smem, A, Wb, bq, qb, nullptr, 512, 0, M, r0, c0, false);
    else if (sel == 1)
      gemm_core(smem, A, Wb + 262144, bk, nullptr, kv, 1024, 0, M, r0, c0, false);
    else
      gemm_core(smem, A, Wb + 2 * 262144, bv, nullptr, kv, 1024, 512, M, r0, c0, false);
    return;
  }

  // ---- topk over precomputed packed centroids ----
  int n = (by - 12) * gridDim.x + blockIdx.x;
  if (n >= N) return;

  unsigned* wh   = (unsigned*)smem;            // [4][1024] packed, 16 KB
  unsigned* tieB = (unsigned*)(smem + 16384);  // 1024 bits, 4 KB
  unsigned* tieI = (unsigned*)(smem + 20480);  // 1024 idx,  4 KB

  int t = threadIdx.x;
  int lane = t & 63, wid = t >> 6;
  const float4* cq = (const float4*)cent;
  float4 c = cq[n];
  float cx = c.x, cy = c.y, cz = c.z;

  // zero wave-private hists (4096 words / 256 thr = 16 each)
  #pragma unroll
  for (int i = 0; i < 16; ++i) wh[t + i * 256] = 0;

  unsigned bits[8];
  #pragma unroll
  for (int r = 0; r < 8; ++r) {
    int m = t + (r << 8);
    unsigned b = 0xFFFFFFFFu;
    if (m < N) {
      float4 cm = cq[m];
      float dx = cx - cm.x, dy = cy - cm.y, dz = cz - cm.z;
      float dist = sqrtf(dx*dx + dy*dy + dz*dz);
      b = __float_as_uint(dist);
    }
    bits[r] = b;
  }
  __syncthreads();

  // build: wave-private packed histogram, bin = bits >> 20 (0..2047)
  unsigned* myh = wh + (wid << 10);
  #pragma unroll
  for (int r = 0; r < 8; ++r) {
    if (bits[r] != 0xFFFFFFFFu) {
      unsigned bin = bits[r] >> 20;
      atomicAdd(&myh[bin >> 1], 1u << ((bin & 1) << 4));
    }
  }
  __syncthreads();

  // boundary-bin search: thread t owns bins [8t, 8t+8) = words [4t, 4t+4)
  unsigned bc[8];
  unsigned tot = 0;
  #pragma unroll
  for (int w = 0; w < 4; ++w) {
    int iw = (t << 2) + w;
    unsigned s = wh[iw] + wh[1024 + iw] + wh[2048 + iw] + wh[3072 + iw];
    bc[w * 2]     = s & 0xFFFFu;
    bc[w * 2 + 1] = s >> 16;
    tot += (s & 0xFFFFu) + (s >> 16);
  }
  unsigned scan = tot;
  #pragma unroll
  for (int o = 1; o < 64; o <<= 1) {
    unsigned u = __shfl_up(scan, o);
    if (lane >= o) scan += u;
  }
  if (lane == 63) waveSums[wid] = scan;
  __syncthreads();
  unsigned off = 0;
  for (int w = 0; w < wid; ++w) off += waveSums[w];
  unsigned incl = scan + off;
  unsigned excl = incl - tot;
  if (excl < NN_K && incl >= NN_K) {
    unsigned cacc = excl;
    #pragma unroll
    for (int b = 0; b < 8; ++b) {
      if (cacc + bc[b] >= NN_K) { selB = (unsigned)(t * 8 + b); selNeed = NN_K - cacc; break; }
      cacc += bc[b];
    }
  }
  if (t == 0) { cnt = 0; tcnt = 0; }
  __syncthreads();

  // collect: below-bin -> direct emit (set semantics); boundary-bin -> tie buf
  unsigned B = selB;
  #pragma unroll
  for (int r = 0; r < 8; ++r) {
    if (bits[r] != 0xFFFFFFFFu) {
      unsigned bin = bits[r] >> 20;
      if (bin < B) {
        unsigned slot = atomicAdd(&cnt, 1u);
        topk[n * NN_K + slot] = t + (r << 8);
      } else if (bin == B) {
        unsigned tp = atomicAdd(&tcnt, 1u);
        if (tp < 1024u) { tieB[tp] = bits[r]; tieI[tp] = (unsigned)(t + (r << 8)); }
      }
    }
  }
  __syncthreads();

  // exact (bits, idx) rank of boundary candidates, wave 0, lane-per-candidate
  if (t < 64) {
    unsigned base = cnt;
    unsigned need = selNeed;
    unsigned tn = tcnt > 1024u ? 1024u : tcnt;
    for (unsigned j = lane; j < tn; j += 64) {
      unsigned kb = tieB[j], ki = tieI[j];
      unsigned rank = 0;
      for (unsigned i = 0; i < tn; ++i) {
        unsigned ib = tieB[i];
        rank += (ib < kb) || (ib == kb && tieI[i] < ki);
      }
      if (rank < need) topk[n * NN_K + base + rank] = (int)ki;
    }
  }
}

__global__ __launch_bounds__(256) void out_mfma(
    const short* __restrict__ A, const short* __restrict__ Wb,
    const float* __restrict__ bias, float* __restrict__ out, int M)
{
  __shared__ __align__(16) char smem[24576];
  gemm_core(smem, A, Wb + (size_t)3 * 262144, bias, out, nullptr, 512, 0, M,
            blockIdx.x * 64, blockIdx.y * 128, true);
}

// ---------------------------------------------------------------------------
// Kernel 3: sparse top-K attention, lane-per-key scores, b64 LDS reads.
// (R2 staged variant — destaging regressed 2.2 µs in R5.)
// ---------------------------------------------------------------------------
__global__ __launch_bounds__(512) void attn_kernel(
    const float* __restrict__ qb, const short* __restrict__ kv,
    const int* __restrict__ topk, short* __restrict__ ctx_bf, int N)
{
  __shared__ short klds[32 * 512];     // 32 KB, XOR-4 swizzled rows
  __shared__ int sidx[NN_K];
  __shared__ float plds[8 * 32];

  int n = blockIdx.x;
  int tid = threadIdx.x;
  size_t rb = (size_t)n * E_DIM;
  if (n >= N) { ctx_bf[rb + tid] = 0; return; }

  if (tid < NN_K) sidx[tid] = topk[n * NN_K + tid];
  __syncthreads();

  int h = tid >> 6, lane = tid & 63;
  int jk = lane & 31, half = lane >> 5;
  int dbase = h * 64 + half * 32;

  // ---- preload q head-slice to regs ----
  float qv[32];
  {
    const float4* qs = (const float4*)(qb + rb + dbase);
    #pragma unroll
    for (int b = 0; b < 8; ++b) {
      float4 f = qs[b];
      qv[b*4+0] = f.x; qv[b*4+1] = f.y; qv[b*4+2] = f.z; qv[b*4+3] = f.w;
    }
  }

  // ---- stage k rows (XOR-4 swizzle) ----
  {
    int j = tid >> 4, a = tid & 15;
    const short8* src = (const short8*)(kv + (size_t)sidx[j] * 1024 + a * 32);
    int sw = 4 * (j & 15);
    short* row = &klds[j * 512];
    #pragma unroll
    for (int b = 0; b < 4; ++b) {
      short8 val = src[b];
      int d0 = a * 32 + b * 8;
      *(short4*)&row[(d0    ) ^ sw] = *(const short4*)&val;
      *(short4*)&row[(d0 + 4) ^ sw] = *((const short4*)&val + 1);
    }
  }
  __syncthreads();

  // ---- scores: lane (jk,half) dot over its 32 dims, b64 LDS reads ----
  float s = 0.f;
  {
    int sw = 4 * (jk & 15);
    const short* krow = &klds[jk * 512];
    #pragma unroll
    for (int i4 = 0; i4 < 8; ++i4) {
      short4 kkv = *(const short4*)&krow[(dbase + i4 * 4) ^ sw];
      s += qv[i4*4+0] * bf2f_bits(kkv.x) + qv[i4*4+1] * bf2f_bits(kkv.y)
         + qv[i4*4+2] * bf2f_bits(kkv.z) + qv[i4*4+3] * bf2f_bits(kkv.w);
    }
  }
  s += __shfl_xor(s, 32);
  s *= 0.125f;

  // ---- softmax over 32 keys ----
  float mx = s;
  #pragma unroll
  for (int o = 16; o > 0; o >>= 1) mx = fmaxf(mx, __shfl_xor(mx, o));
  float p = expf(s - mx);
  float l = p;
  #pragma unroll
  for (int o = 16; o > 0; o >>= 1) l += __shfl_xor(l, o);
  p *= (1.0f / l);
  if (half == 0) plds[h * 32 + jk] = p;
  __syncthreads();

  float pv[32];
  #pragma unroll
  for (int b = 0; b < 8; ++b) {
    float4 f = *(const float4*)&plds[h * 32 + b * 4];
    pv[b*4+0] = f.x; pv[b*4+1] = f.y; pv[b*4+2] = f.z; pv[b*4+3] = f.w;
  }

  // ---- ctx: lane = dim, coalesced bf16 v gathers ----
  int off = 512 + h * 64 + lane;
  float acc = 0.f;
  #pragma unroll
  for (int j = 0; j < NN_K; ++j)
    acc += pv[j] * bf2f_bits(kv[(size_t)sidx[j] * 1024 + off]);
  ctx_bf[rb + h * 64 + lane] = (short)f2bf(acc);
}

// ---------------------------------------------------------------------------
extern "C" void kernel_launch(void* const* d_in, const int* in_sizes, int n_in,
                              void* d_out, int out_size, void* d_ws, size_t ws_size,
                              hipStream_t stream) {
  const float* x       = (const float*)d_in[0];
  const float* coords9 = (const float*)d_in[1];
  const float* prompt  = (const float*)d_in[2];
  const float* pos_w1  = (const float*)d_in[3];
  const float* pos_b1  = (const float*)d_in[4];
  const float* ln_g    = (const float*)d_in[5];
  const float* ln_b    = (const float*)d_in[6];
  const float* wq      = (const float*)d_in[7];
  const float* wk      = (const float*)d_in[8];
  const float* wv      = (const float*)d_in[9];
  const float* bq      = (const float*)d_in[10];
  const float* bk      = (const float*)d_in[11];
  const float* bv      = (const float*)d_in[12];
  const float* wo      = (const float*)d_in[13];
  const float* bo      = (const float*)d_in[14];

  int N = in_sizes[1] / 9;                       // 2000
  int Mpad = (N + 127) & ~127;                   // 2048
  size_t PE = (size_t)Mpad * E_DIM;

  char* p = (char*)d_ws;
  short* pos_bf = (short*)p; p += PE * 2;                      // 2 MB
  short* w_bf   = (short*)p; p += (size_t)4 * 512 * 512 * 2;   // 2 MB
  float* qb     = (float*)p; p += PE * 4;                      // 4 MB
  short* kv_bf  = (short*)p; p += PE * 2 * 2;                  // 4 MB (k|v)
  short* ctx_bf = (short*)p; p += PE * 2;                      // 2 MB
  int*   topk   = (int*)p;   p += (size_t)Mpad * NN_K * 4;     // 256 KB
  float* cent   = (float*)p;                                   // Mpad float4s

  front_kernel<<<256 + Mpad, 256, 0, stream>>>(
      x, coords9, prompt, pos_w1, pos_b1, ln_g, ln_b,
      wq, wk, wv, wo, w_bf, pos_bf, cent, N);

  int gx = Mpad / 64;                            // 32
  dim3 gq(gx, 12 + (N + gx - 1) / gx);           // 12 GEMM slices + 63 topk slices
  qkv_topk<<<gq, 256, 0, stream>>>(pos_bf, w_bf, bq, bk, bv, qb, kv_bf,
                                   cent, topk, Mpad, N);
  attn_kernel<<<Mpad, 512, 0, stream>>>(qb, kv_bf, topk, ctx_bf, N);

  dim3 go(Mpad / 64, 4);
  out_mfma<<<go, 256, 0, stream>>>(ctx_bf, w_bf, bo, (float*)d_out, N);
}